// Round 3
// baseline (282.486 us; speedup 1.0000x reference)
//
#include <hip/hip_runtime.h>
#include <hip/hip_bf16.h>

#define HID 64
#define TPAD 68   // LDS row pad (floats): 16B-aligned rows, limits read conflicts to ~8-way

__device__ __forceinline__ unsigned int pack2bf(float lo, float hi) {
    // round-to-nearest-even bf16 pair packed into one dword (lo = even col)
    unsigned int ul = __float_as_uint(lo), uh = __float_as_uint(hi);
    unsigned int rl = (ul + 0x7fffu + ((ul >> 16) & 1u)) >> 16;
    unsigned int rh = (uh + 0x7fffu + ((uh >> 16) & 1u)) & 0xffff0000u;
    return rl | rh;
}

// Kernel 0: W1T[h][j][k] = W1[h*64+k][j]  (so each output column is a
// contiguous 64-float row -> wave-uniform s_load in node_proj)
__global__ __launch_bounds__(256) void transpose_w1_kernel(
    const float* __restrict__ W1, float* __restrict__ W1T)
{
    const int t = blockIdx.x * 256 + threadIdx.x;   // 8192 elements
    const int h = t >> 12, j = (t >> 6) & 63, k = t & 63;
    W1T[t] = W1[(h * HID + k) * HID + j];
}

// Kernel 1: per-node projections, lane = node.
//   A[n][j] = sum_k z[n][k] * W1[k][j]
//   B[n][j] = sum_k z[n][k] * W1[64+k][j] + b1[j]
// Block stages 128 z-rows into LDS (coalesced); each lane copies its node's
// row into 64 VGPRs (all static indices); inner loop is pure VGPR x SGPR FMA.
// Wave w of 4: node group = w>>1, half (A/B) = w&1.
__global__ __launch_bounds__(256) void node_proj_kernel(
    const float* __restrict__ z, const float* __restrict__ W1T,
    const float* __restrict__ b1,
    unsigned short* __restrict__ A, unsigned short* __restrict__ B,
    int n_nodes)
{
    __shared__ float lds[128 * TPAD];
    const int t    = threadIdx.x;
    const int lane = t & 63;
    const int wv   = __builtin_amdgcn_readfirstlane(t >> 6);  // provably uniform
    const int base = blockIdx.x * 128;

    // stage 128 rows x 64 floats, coalesced float4
#pragma unroll
    for (int i = 0; i < 8; ++i) {
        const int flat = t + i * 256;         // float4 id: row = flat/16, c4 = flat%16
        const int row = flat >> 4, c4 = flat & 15;
        int gr = base + row;
        if (gr >= n_nodes) gr = n_nodes - 1;  // clamp (dup loads, stores guarded)
        const float4 v = *(const float4*)(z + (size_t)gr * HID + c4 * 4);
        *(float4*)(lds + row * TPAD + c4 * 4) = v;
    }
    __syncthreads();

    // each lane pulls its node's row into registers (static indexing only)
    const int nrow = ((wv >> 1) << 6) | lane;
    float zr[HID];
#pragma unroll
    for (int k4 = 0; k4 < 16; ++k4) {
        const float4 v = *(const float4*)(lds + nrow * TPAD + k4 * 4);
        zr[4 * k4 + 0] = v.x; zr[4 * k4 + 1] = v.y;
        zr[4 * k4 + 2] = v.z; zr[4 * k4 + 3] = v.w;
    }

    const int hsel = wv & 1;                       // uniform
    const float* __restrict__ wbase = W1T + (hsel << 12);
    unsigned short* __restrict__ dstbase = hsel ? B : A;
    const int node = base + nrow;
    const bool ok = node < n_nodes;
    unsigned int* __restrict__ drow = (unsigned int*)(dstbase + (size_t)node * HID);

    for (int j = 0; j < HID; j += 2) {
        const float* __restrict__ w0 = wbase + j * HID;       // uniform -> s_load
        const float* __restrict__ w1 = w0 + HID;
        float a0 = hsel ? b1[j]     : 0.0f;                   // uniform s_load
        float b0 = hsel ? b1[j + 1] : 0.0f;
        float a1 = 0.0f, b1v = 0.0f;
#pragma unroll
        for (int k = 0; k < HID; k += 2) {
            a0  = fmaf(zr[k],     w0[k],     a0);
            a1  = fmaf(zr[k + 1], w0[k + 1], a1);
            b0  = fmaf(zr[k],     w1[k],     b0);
            b1v = fmaf(zr[k + 1], w1[k + 1], b1v);
        }
        const unsigned int p = pack2bf(a0 + a1, b0 + b1v);
        if (ok) drow[j >> 1] = p;
    }
}

// Kernel 2: per-edge  out[e] = relu(A[row[e]] + B[col[e]]) . W2 + b2
// 64 edges per wave chunk. 8-lane groups, 8 edges per g-iteration; each lane
// gathers a uint4 (16B = 8 bf16 dims). All 16 gathers issued before use.
__global__ __launch_bounds__(256) void edge_kernel(
    const int* __restrict__ row, const int* __restrict__ col,
    const unsigned short* __restrict__ A, const unsigned short* __restrict__ B,
    const float* __restrict__ W2, const float* __restrict__ b2,
    float* __restrict__ out, int E)
{
    const int tid    = blockIdx.x * blockDim.x + threadIdx.x;
    const int lane   = tid & 63;
    const int gwave  = tid >> 6;
    const int nwaves = (gridDim.x * blockDim.x) >> 6;
    const int sub    = lane >> 3;   // 0..7: which edge of the group of 8
    const int l8     = lane & 7;    // dim slice: dims l8*8 .. l8*8+7

    float w2r[8];
#pragma unroll
    for (int i = 0; i < 8; ++i) w2r[i] = W2[l8 * 8 + i];
    const float b2v = b2[0];

    const int nchunks = E >> 6;
    for (int ch = gwave; ch < nchunks; ch += nwaves) {
        const int ebase = ch << 6;
        const int r = row[ebase + lane];   // coalesced
        const int c = col[ebase + lane];

        uint4 av[8], bv[8];
#pragma unroll
        for (int g = 0; g < 8; ++g) {
            const int ri = __shfl(r, g * 8 + sub);
            const int ci = __shfl(c, g * 8 + sub);
            av[g] = *(const uint4*)(A + (size_t)ri * HID + l8 * 8);
            bv[g] = *(const uint4*)(B + (size_t)ci * HID + l8 * 8);
        }

#pragma unroll
        for (int g = 0; g < 8; ++g) {
            const unsigned int* au = (const unsigned int*)&av[g];
            const unsigned int* bu = (const unsigned int*)&bv[g];
            float acc = 0.f;
#pragma unroll
            for (int i = 0; i < 4; ++i) {
                float alo = __uint_as_float(au[i] << 16);
                float ahi = __uint_as_float(au[i] & 0xffff0000u);
                float blo = __uint_as_float(bu[i] << 16);
                float bhi = __uint_as_float(bu[i] & 0xffff0000u);
                float slo = fmaxf(alo + blo, 0.f);
                float shi = fmaxf(ahi + bhi, 0.f);
                acc = fmaf(slo, w2r[2 * i + 0], acc);
                acc = fmaf(shi, w2r[2 * i + 1], acc);
            }
            acc += __shfl_xor(acc, 4);
            acc += __shfl_xor(acc, 2);
            acc += __shfl_xor(acc, 1);
            if (l8 == 0) out[ebase + g * 8 + sub] = acc + b2v;
        }
    }
}

extern "C" void kernel_launch(void* const* d_in, const int* in_sizes, int n_in,
                              void* d_out, int out_size, void* d_ws, size_t ws_size,
                              hipStream_t stream) {
    const float* z  = (const float*)d_in[0];
    const int*   ei = (const int*)d_in[1];
    const float* W1 = (const float*)d_in[2];
    const float* b1 = (const float*)d_in[3];
    const float* W2 = (const float*)d_in[4];
    const float* b2 = (const float*)d_in[5];
    float* out = (float*)d_out;

    const int n_nodes = in_sizes[0] / HID;     // 100000
    const int E       = in_sizes[1] / 2;       // 3200000
    const int* row = ei;
    const int* col = ei + E;

    unsigned short* A = (unsigned short*)d_ws;                 // [n_nodes][64] bf16
    unsigned short* B = A + (size_t)n_nodes * HID;             // [n_nodes][64] bf16
    float* W1T = (float*)(B + (size_t)n_nodes * HID);          // [2][64][64] f32

    transpose_w1_kernel<<<32, 256, 0, stream>>>(W1, W1T);
    const int nblocks = (n_nodes + 127) / 128;                 // 782
    node_proj_kernel<<<nblocks, 256, 0, stream>>>(z, W1T, b1, A, B, n_nodes);
    edge_kernel<<<2048, 256, 0, stream>>>(row, col, A, B, W2, b2, out, E);
}

// Round 4
// 268.407 us; speedup vs baseline: 1.0525x; 1.0525x over previous
//
#include <hip/hip_runtime.h>
#include <hip/hip_bf16.h>

#define HID 64

typedef __attribute__((ext_vector_type(8))) short bf16x8;
typedef __attribute__((ext_vector_type(4))) float f32x4;

__device__ __forceinline__ float bf2f(unsigned short x) {
    return __uint_as_float(((unsigned int)x) << 16);
}

__device__ __forceinline__ unsigned short f2bf(float f) {
    // round-to-nearest-even bf16
    unsigned int u = __float_as_uint(f);
    return (unsigned short)((u + 0x7fffu + ((u >> 16) & 1u)) >> 16);
}

__device__ __forceinline__ unsigned int pack2bf(float lo, float hi) {
    unsigned int ul = __float_as_uint(lo), uh = __float_as_uint(hi);
    unsigned int rl = (ul + 0x7fffu + ((ul >> 16) & 1u)) >> 16;
    unsigned int rh = (uh + 0x7fffu + ((uh >> 16) & 1u)) & 0xffff0000u;
    return rl | rh;
}

// W1bt[c][k] = bf16(W1[(c>=64 ? 64 : 0) + k][c & 63]), c=0..127, k=0..63.
// Row-major 128x64 bf16 so each output column's 64 weights are contiguous.
__global__ __launch_bounds__(256) void prep_weights(
    const float* __restrict__ W1, unsigned short* __restrict__ W1bt)
{
    const int t = blockIdx.x * 256 + threadIdx.x;   // 8192
    const int c = t >> 6, k = t & 63;
    W1bt[t] = f2bf(W1[(((c >> 6) << 6) + k) * HID + (c & 63)]);
}

// MFMA node projection: C[100000 x 128] = z[100000 x 64] @ W[64 x 128]
// Split outputs: cols 0-31 -> A0, 32-63 -> A1, 64-95 -> B0(+b1), 96-127 -> B1(+b1).
// Per wave: one 16-node M-tile per iteration; 8 N-tiles x 2 K-steps of
// mfma_f32_16x16x32_bf16. B-frags (weights) live in VGPRs for the whole kernel.
__global__ __launch_bounds__(256) void node_proj_mfma(
    const float* __restrict__ z, const unsigned short* __restrict__ W1bt,
    const float* __restrict__ b1,
    unsigned short* __restrict__ A0, unsigned short* __restrict__ A1,
    unsigned short* __restrict__ B0, unsigned short* __restrict__ B1,
    int n_tiles)
{
    const int tid  = blockIdx.x * 256 + threadIdx.x;
    const int lane = tid & 63;
    const int wv   = tid >> 6;
    const int nw   = (gridDim.x * 256) >> 6;
    const int q    = lane >> 4;      // k-group
    const int r    = lane & 15;      // A row / B col within tile

    // B-operand fragments: lane holds W[ks*32 + 8q + i][ct*16 + r], i=0..7
    bf16x8 wf[8][2];
#pragma unroll
    for (int ct = 0; ct < 8; ++ct)
#pragma unroll
        for (int ks = 0; ks < 2; ++ks)
            wf[ct][ks] = *(const bf16x8*)(W1bt + (ct * 16 + r) * HID + ks * 32 + q * 8);

    float bias[4];
#pragma unroll
    for (int i = 0; i < 4; ++i) bias[i] = b1[i * 16 + r];

    unsigned short* const dsts[8] = {A0, A0, A1, A1, B0, B0, B1, B1};

    for (int t = wv; t < n_tiles; t += nw) {
        const int rowb = t * 16;
        const float* zb = z + (size_t)(rowb + r) * HID;

        // A-operand: lane holds bf16(z[rowb + r][ks*32 + 8q + i]), i=0..7
        bf16x8 af[2];
#pragma unroll
        for (int ks = 0; ks < 2; ++ks) {
            const float4 f0 = *(const float4*)(zb + ks * 32 + q * 8);
            const float4 f1 = *(const float4*)(zb + ks * 32 + q * 8 + 4);
            unsigned int u[4];
            u[0] = pack2bf(f0.x, f0.y); u[1] = pack2bf(f0.z, f0.w);
            u[2] = pack2bf(f1.x, f1.y); u[3] = pack2bf(f1.z, f1.w);
            af[ks] = *(bf16x8*)u;
        }

#pragma unroll
        for (int ct = 0; ct < 8; ++ct) {
            f32x4 acc = {0.f, 0.f, 0.f, 0.f};
            acc = __builtin_amdgcn_mfma_f32_16x16x32_bf16(af[0], wf[ct][0], acc, 0, 0, 0);
            acc = __builtin_amdgcn_mfma_f32_16x16x32_bf16(af[1], wf[ct][1], acc, 0, 0, 0);
            const float bv = (ct >= 4) ? bias[ct - 4] : 0.0f;
            unsigned short* __restrict__ dst = dsts[ct];
            const int colw = (ct & 1) * 16 + r;
            // C/D map (HW-verified): col = lane&15, row = (lane>>4)*4 + reg
#pragma unroll
            for (int j = 0; j < 4; ++j) {
                const int node = rowb + q * 4 + j;
                dst[(size_t)node * 32 + colw] = f2bf(acc[j] + bv);
            }
        }
    }
}

// Edge pass over one 32-dim half:  out[e] (+)= sum_j w2[j]*relu(XA[r][j]+XB[c][j])
// 128 edges per chunk; 4-lane groups each read a full 64B row slice (uint4).
// PASS 0: out = partial + b2.  PASS 1: out += partial.
template <int PASS>
__global__ __launch_bounds__(256) void edge_half_kernel(
    const int* __restrict__ row, const int* __restrict__ col,
    const unsigned short* __restrict__ XA, const unsigned short* __restrict__ XB,
    const float* __restrict__ W2, const float* __restrict__ b2,
    float* __restrict__ out, int nchunks)
{
    const int tid  = blockIdx.x * 256 + threadIdx.x;
    const int lane = tid & 63;
    const int wv   = tid >> 6;
    const int nw   = (gridDim.x * 256) >> 6;
    const int sub  = lane >> 2;    // 0..15: edge within group-of-16
    const int l4   = lane & 3;     // 16B slice of the 64B row

    float w2r[8];
#pragma unroll
    for (int i = 0; i < 8; ++i) w2r[i] = W2[PASS * 32 + l4 * 8 + i];
    const float b2v = b2[0];

    for (int ch = wv; ch < nchunks; ch += nw) {
        const int ebase = ch << 7;
        const int r0 = row[ebase + lane],      c0 = col[ebase + lane];
        const int r1 = row[ebase + 64 + lane], c1 = col[ebase + 64 + lane];
        float o0 = 0.f, o1 = 0.f;
        if (PASS == 1) { o0 = out[ebase + lane]; o1 = out[ebase + 64 + lane]; }

        uint4 av[8], bv[8];
#pragma unroll
        for (int g = 0; g < 8; ++g) {
            const int e  = (g & 3) * 16 + sub;
            const int ri = (g < 4) ? __shfl(r0, e) : __shfl(r1, e);
            const int ci = (g < 4) ? __shfl(c0, e) : __shfl(c1, e);
            av[g] = *(const uint4*)(XA + (size_t)ri * 32 + l4 * 8);
            bv[g] = *(const uint4*)(XB + (size_t)ci * 32 + l4 * 8);
        }

#pragma unroll
        for (int g = 0; g < 8; ++g) {
            const unsigned int* au = (const unsigned int*)&av[g];
            const unsigned int* bu = (const unsigned int*)&bv[g];
            float acc = 0.f;
#pragma unroll
            for (int i = 0; i < 4; ++i) {
                float alo = __uint_as_float(au[i] << 16);
                float ahi = __uint_as_float(au[i] & 0xffff0000u);
                float blo = __uint_as_float(bu[i] << 16);
                float bhi = __uint_as_float(bu[i] & 0xffff0000u);
                acc = fmaf(fmaxf(alo + blo, 0.f), w2r[2 * i + 0], acc);
                acc = fmaf(fmaxf(ahi + bhi, 0.f), w2r[2 * i + 1], acc);
            }
            acc += __shfl_xor(acc, 1);
            acc += __shfl_xor(acc, 2);
            const int eo   = (g & 3) * 16 + sub;
            const float bs = (PASS == 0) ? b2v
                             : ((g < 4) ? __shfl(o0, eo) : __shfl(o1, eo));
            if (l4 == 0) out[ebase + ((g < 4) ? 0 : 64) + eo] = acc + bs;
        }
    }
}

extern "C" void kernel_launch(void* const* d_in, const int* in_sizes, int n_in,
                              void* d_out, int out_size, void* d_ws, size_t ws_size,
                              hipStream_t stream) {
    const float* z  = (const float*)d_in[0];
    const int*   ei = (const int*)d_in[1];
    const float* W1 = (const float*)d_in[2];
    const float* b1 = (const float*)d_in[3];
    const float* W2 = (const float*)d_in[4];
    const float* b2 = (const float*)d_in[5];
    float* out = (float*)d_out;

    const int n_nodes = in_sizes[0] / HID;     // 100000
    const int E       = in_sizes[1] / 2;       // 3200000
    const int* row = ei;
    const int* col = ei + E;

    const size_t arr = (size_t)n_nodes * 32;   // ushorts per half-array
    unsigned short* A0 = (unsigned short*)d_ws;
    unsigned short* A1 = A0 + arr;
    unsigned short* B0 = A1 + arr;
    unsigned short* B1 = B0 + arr;
    unsigned short* W1bt = B1 + arr;           // 128*64 bf16 = 16KB

    prep_weights<<<32, 256, 0, stream>>>(W1, W1bt);
    node_proj_mfma<<<256, 256, 0, stream>>>(z, W1bt, b1, A0, A1, B0, B1, n_nodes / 16);
    const int nchunks = E >> 7;                // 25000
    edge_half_kernel<0><<<2048, 256, 0, stream>>>(row, col, A0, B0, W2, b2, out, nchunks);
    edge_half_kernel<1><<<2048, 256, 0, stream>>>(row, col, A1, B1, W2, b2, out, nchunks);
}

// Round 5
// 206.291 us; speedup vs baseline: 1.3694x; 1.3011x over previous
//
#include <hip/hip_runtime.h>
#include <hip/hip_bf16.h>

#define HID 64

typedef __attribute__((ext_vector_type(8))) short bf16x8;
typedef __attribute__((ext_vector_type(4))) float f32x4;

__device__ __forceinline__ unsigned short f2bf(float f) {
    // round-to-nearest-even bf16
    unsigned int u = __float_as_uint(f);
    return (unsigned short)((u + 0x7fffu + ((u >> 16) & 1u)) >> 16);
}

__device__ __forceinline__ unsigned int pack2bf(float lo, float hi) {
    unsigned int ul = __float_as_uint(lo), uh = __float_as_uint(hi);
    unsigned int rl = (ul + 0x7fffu + ((ul >> 16) & 1u)) >> 16;
    unsigned int rh = (uh + 0x7fffu + ((uh >> 16) & 1u)) & 0xffff0000u;
    return rl | rh;
}

// W1bt[c][k] = bf16(W1[(c>=64 ? 64 : 0) + k][c & 63]), c=0..127, k=0..63.
__global__ __launch_bounds__(256) void prep_weights(
    const float* __restrict__ W1, unsigned short* __restrict__ W1bt)
{
    const int t = blockIdx.x * 256 + threadIdx.x;   // 8192
    const int c = t >> 6, k = t & 63;
    W1bt[t] = f2bf(W1[(((c >> 6) << 6) + k) * HID + (c & 63)]);
}

// MFMA node projection: C[100000 x 128] = z[100000 x 64] @ W[64 x 128]
// cols 0-63 -> A row (bf16, 128B), cols 64-127 -> B row (+b1).
// Per wave-iteration: one 16-node M-tile; 8 N-tiles x 2 K-steps of
// mfma_f32_16x16x32_bf16. Weight fragments live in VGPRs for the whole kernel.
__global__ __launch_bounds__(256) void node_proj_mfma(
    const float* __restrict__ z, const unsigned short* __restrict__ W1bt,
    const float* __restrict__ b1,
    unsigned short* __restrict__ A, unsigned short* __restrict__ B,
    int n_tiles)
{
    const int tid  = blockIdx.x * 256 + threadIdx.x;
    const int lane = tid & 63;
    const int wv   = tid >> 6;
    const int nw   = (gridDim.x * 256) >> 6;
    const int q    = lane >> 4;      // k-group
    const int r    = lane & 15;      // A row / B col within tile

    // B-operand fragments: lane holds W[ks*32 + 8q + i][ct*16 + r], i=0..7
    bf16x8 wf[8][2];
#pragma unroll
    for (int ct = 0; ct < 8; ++ct)
#pragma unroll
        for (int ks = 0; ks < 2; ++ks)
            wf[ct][ks] = *(const bf16x8*)(W1bt + (ct * 16 + r) * HID + ks * 32 + q * 8);

    float bias[4];
#pragma unroll
    for (int i = 0; i < 4; ++i) bias[i] = b1[i * 16 + r];

    for (int t = wv; t < n_tiles; t += nw) {
        const int rowb = t * 16;
        const float* zb = z + (size_t)(rowb + r) * HID;

        // A-operand: lane holds bf16(z[rowb + r][ks*32 + 8q + i]), i=0..7
        bf16x8 af[2];
#pragma unroll
        for (int ks = 0; ks < 2; ++ks) {
            const float4 f0 = *(const float4*)(zb + ks * 32 + q * 8);
            const float4 f1 = *(const float4*)(zb + ks * 32 + q * 8 + 4);
            unsigned int u[4];
            u[0] = pack2bf(f0.x, f0.y); u[1] = pack2bf(f0.z, f0.w);
            u[2] = pack2bf(f1.x, f1.y); u[3] = pack2bf(f1.z, f1.w);
            af[ks] = *(bf16x8*)u;
        }

#pragma unroll
        for (int ct = 0; ct < 8; ++ct) {
            f32x4 acc = {0.f, 0.f, 0.f, 0.f};
            acc = __builtin_amdgcn_mfma_f32_16x16x32_bf16(af[0], wf[ct][0], acc, 0, 0, 0);
            acc = __builtin_amdgcn_mfma_f32_16x16x32_bf16(af[1], wf[ct][1], acc, 0, 0, 0);
            const bool isB = (ct >= 4);
            const float bv = isB ? bias[ct & 3] : 0.0f;
            unsigned short* __restrict__ dst = isB ? B : A;
            const int colw = (ct & 3) * 16 + r;
            // C/D map (HW-verified): col = lane&15, row = (lane>>4)*4 + reg
#pragma unroll
            for (int j = 0; j < 4; ++j) {
                const int node = rowb + q * 4 + j;
                dst[(size_t)node * HID + colw] = f2bf(acc[j] + bv);
            }
        }
    }
}

// Edge kernel: out[e] = relu(A[row[e]] + B[col[e]]) . W2 + b2
// 64 edges per wave chunk. 8-lane groups, 8 edges per g-iteration; each lane
// gathers a uint4 (16B = 8 bf16 dims) of its group's 128B A/B rows. All 16
// gathers issued before any consumption. E is a multiple of 64.
__global__ __launch_bounds__(256) void edge_kernel(
    const int* __restrict__ row, const int* __restrict__ col,
    const unsigned short* __restrict__ A, const unsigned short* __restrict__ B,
    const float* __restrict__ W2, const float* __restrict__ b2,
    float* __restrict__ out, int E)
{
    const int tid    = blockIdx.x * blockDim.x + threadIdx.x;
    const int lane   = tid & 63;
    const int gwave  = tid >> 6;
    const int nwaves = (gridDim.x * blockDim.x) >> 6;
    const int sub    = lane >> 3;   // 0..7: which edge of the group of 8
    const int l8     = lane & 7;    // dim slice: dims l8*8 .. l8*8+7

    float w2r[8];
#pragma unroll
    for (int i = 0; i < 8; ++i) w2r[i] = W2[l8 * 8 + i];
    const float b2v = b2[0];

    const int nchunks = E >> 6;
    for (int ch = gwave; ch < nchunks; ch += nwaves) {
        const int ebase = ch << 6;
        const int r = row[ebase + lane];   // coalesced
        const int c = col[ebase + lane];

        uint4 av[8], bv[8];
#pragma unroll
        for (int g = 0; g < 8; ++g) {
            const int ri = __shfl(r, g * 8 + sub);
            const int ci = __shfl(c, g * 8 + sub);
            av[g] = *(const uint4*)(A + (size_t)ri * HID + l8 * 8);
            bv[g] = *(const uint4*)(B + (size_t)ci * HID + l8 * 8);
        }

#pragma unroll
        for (int g = 0; g < 8; ++g) {
            const unsigned int* au = (const unsigned int*)&av[g];
            const unsigned int* bu = (const unsigned int*)&bv[g];
            float acc = 0.f;
#pragma unroll
            for (int i = 0; i < 4; ++i) {
                float alo = __uint_as_float(au[i] << 16);
                float ahi = __uint_as_float(au[i] & 0xffff0000u);
                float blo = __uint_as_float(bu[i] << 16);
                float bhi = __uint_as_float(bu[i] & 0xffff0000u);
                acc = fmaf(fmaxf(alo + blo, 0.f), w2r[2 * i + 0], acc);
                acc = fmaf(fmaxf(ahi + bhi, 0.f), w2r[2 * i + 1], acc);
            }
            acc += __shfl_xor(acc, 4);
            acc += __shfl_xor(acc, 2);
            acc += __shfl_xor(acc, 1);
            if (l8 == 0) out[ebase + g * 8 + sub] = acc + b2v;
        }
    }
}

extern "C" void kernel_launch(void* const* d_in, const int* in_sizes, int n_in,
                              void* d_out, int out_size, void* d_ws, size_t ws_size,
                              hipStream_t stream) {
    const float* z  = (const float*)d_in[0];
    const int*   ei = (const int*)d_in[1];
    const float* W1 = (const float*)d_in[2];
    const float* b1 = (const float*)d_in[3];
    const float* W2 = (const float*)d_in[4];
    const float* b2 = (const float*)d_in[5];
    float* out = (float*)d_out;

    const int n_nodes = in_sizes[0] / HID;     // 100000
    const int E       = in_sizes[1] / 2;       // 3200000
    const int* row = ei;
    const int* col = ei + E;

    unsigned short* A = (unsigned short*)d_ws;         // [n_nodes][64] bf16 (128B rows)
    unsigned short* B = A + (size_t)n_nodes * HID;     // [n_nodes][64] bf16
    unsigned short* W1bt = B + (size_t)n_nodes * HID;  // 128*64 bf16

    prep_weights<<<32, 256, 0, stream>>>(W1, W1bt);
    node_proj_mfma<<<1024, 256, 0, stream>>>(z, W1bt, b1, A, B, n_nodes / 16);
    edge_kernel<<<2048, 256, 0, stream>>>(row, col, A, B, W2, b2, out, E);
}

// Round 6
// 199.502 us; speedup vs baseline: 1.4160x; 1.0340x over previous
//
#include <hip/hip_runtime.h>
#include <hip/hip_bf16.h>

#define HID 64
#define ZSTRIDE 68   // floats per staged z-row (64 + 4 pad, keeps 16B align)
#define WSTRIDE 72   // ushorts per staged W1 row (64 + 8 pad, keeps 16B align)

typedef __attribute__((ext_vector_type(8))) short bf16x8;
typedef __attribute__((ext_vector_type(4))) float f32x4;

__device__ __forceinline__ unsigned short f2bf(float f) {
    unsigned int u = __float_as_uint(f);
    return (unsigned short)((u + 0x7fffu + ((u >> 16) & 1u)) >> 16);
}

__device__ __forceinline__ unsigned int pack2bf(float lo, float hi) {
    unsigned int ul = __float_as_uint(lo), uh = __float_as_uint(hi);
    unsigned int rl = (ul + 0x7fffu + ((ul >> 16) & 1u)) >> 16;
    unsigned int rh = (uh + 0x7fffu + ((uh >> 16) & 1u)) & 0xffff0000u;
    return rl | rh;
}

// Fused node projection: C[100000 x 128] = z[100000 x 64] @ [W1a | W1b]
// cols 0-63 -> A row (bf16, 128B line), cols 64-127 -> B row (+b1).
// One block = 4 waves = 64 nodes, one shot (no grid-stride). Per block:
//   1) convert W1 (f32, coalesced) -> LDS bf16 [128 cols][64 k]
//   2) stage 64 z-rows -> LDS (coalesced float4)
//   3) each wave: one 16-node M-tile, 8 N-tiles x 2 K-steps of
//      mfma_f32_16x16x32_bf16; weights read once from LDS into VGPRs.
__global__ __launch_bounds__(256) void node_proj_mfma(
    const float* __restrict__ z, const float* __restrict__ W1,
    const float* __restrict__ b1,
    unsigned short* __restrict__ A, unsigned short* __restrict__ B,
    int n_nodes)
{
    __shared__ alignas(16) float          zlds[64 * ZSTRIDE];
    __shared__ alignas(16) unsigned short w1lds[128 * WSTRIDE];

    const int t    = threadIdx.x;
    const int lane = t & 63;
    const int wv   = t >> 6;         // 0..3
    const int q    = lane >> 4;      // k-group
    const int r    = lane & 15;      // A row / B col within tile
    const int base = blockIdx.x * 64;

    // 1) W1 -> LDS bf16, layout w1lds[c][k] = bf16(W1[(c>>6)*64 + k][c&63])
#pragma unroll
    for (int i = 0; i < 32; ++i) {
        const int idx = t + i * 256;          // 0..8191, coalesced read
        const int kk  = idx >> 6;             // W1 row (0..127)
        const int j   = idx & 63;             // W1 col
        const int c   = ((kk >> 6) << 6) | j; // output column 0..127
        w1lds[c * WSTRIDE + (kk & 63)] = f2bf(W1[idx]);
    }

    // 2) stage 64 z-rows (clamped), coalesced float4
#pragma unroll
    for (int i = 0; i < 4; ++i) {
        const int flat = t + i * 256;         // float4 id: row = flat/16
        const int row = flat >> 4, c4 = flat & 15;
        int gr = base + row;
        if (gr >= n_nodes) gr = n_nodes - 1;
        *(float4*)(zlds + row * ZSTRIDE + c4 * 4) =
            *(const float4*)(z + (size_t)gr * HID + c4 * 4);
    }
    __syncthreads();

    // 3) fragments from LDS
    bf16x8 wf[8][2];
#pragma unroll
    for (int ct = 0; ct < 8; ++ct)
#pragma unroll
        for (int ks = 0; ks < 2; ++ks)
            wf[ct][ks] = *(const bf16x8*)(w1lds + (ct * 16 + r) * WSTRIDE + ks * 32 + q * 8);

    bf16x8 af[2];
#pragma unroll
    for (int ks = 0; ks < 2; ++ks) {
        const float* zp = zlds + (wv * 16 + r) * ZSTRIDE + ks * 32 + q * 8;
        const float4 f0 = *(const float4*)zp;
        const float4 f1 = *(const float4*)(zp + 4);
        unsigned int u[4];
        u[0] = pack2bf(f0.x, f0.y); u[1] = pack2bf(f0.z, f0.w);
        u[2] = pack2bf(f1.x, f1.y); u[3] = pack2bf(f1.z, f1.w);
        af[ks] = *(bf16x8*)u;
    }

    float bias[4];
#pragma unroll
    for (int i = 0; i < 4; ++i) bias[i] = b1[i * 16 + r];

    const int rowb = base + wv * 16;
#pragma unroll
    for (int ct = 0; ct < 8; ++ct) {
        f32x4 acc = {0.f, 0.f, 0.f, 0.f};
        acc = __builtin_amdgcn_mfma_f32_16x16x32_bf16(af[0], wf[ct][0], acc, 0, 0, 0);
        acc = __builtin_amdgcn_mfma_f32_16x16x32_bf16(af[1], wf[ct][1], acc, 0, 0, 0);
        const bool isB = (ct >= 4);
        const float bv = isB ? bias[ct & 3] : 0.0f;
        unsigned short* __restrict__ dst = isB ? B : A;
        const int colw = (ct & 3) * 16 + r;
        // C/D map (HW-verified): col = lane&15, row = (lane>>4)*4 + reg
#pragma unroll
        for (int j = 0; j < 4; ++j) {
            const int node = rowb + q * 4 + j;
            if (node < n_nodes) dst[(size_t)node * HID + colw] = f2bf(acc[j] + bv);
        }
    }
}

// Edge kernel (UNCHANGED control): out[e] = relu(A[row[e]] + B[col[e]]) . W2 + b2
// 64 edges per wave chunk. 8-lane groups, 8 edges per g-iteration; each lane
// gathers a uint4 (16B = 8 bf16 dims) of its group's 128B A/B rows. All 16
// gathers issued before any consumption. E is a multiple of 64.
__global__ __launch_bounds__(256) void edge_kernel(
    const int* __restrict__ row, const int* __restrict__ col,
    const unsigned short* __restrict__ A, const unsigned short* __restrict__ B,
    const float* __restrict__ W2, const float* __restrict__ b2,
    float* __restrict__ out, int E)
{
    const int tid    = blockIdx.x * blockDim.x + threadIdx.x;
    const int lane   = tid & 63;
    const int gwave  = tid >> 6;
    const int nwaves = (gridDim.x * blockDim.x) >> 6;
    const int sub    = lane >> 3;   // 0..7: which edge of the group of 8
    const int l8     = lane & 7;    // dim slice: dims l8*8 .. l8*8+7

    float w2r[8];
#pragma unroll
    for (int i = 0; i < 8; ++i) w2r[i] = W2[l8 * 8 + i];
    const float b2v = b2[0];

    const int nchunks = E >> 6;
    for (int ch = gwave; ch < nchunks; ch += nwaves) {
        const int ebase = ch << 6;
        const int r = row[ebase + lane];   // coalesced
        const int c = col[ebase + lane];

        uint4 av[8], bv[8];
#pragma unroll
        for (int g = 0; g < 8; ++g) {
            const int ri = __shfl(r, g * 8 + sub);
            const int ci = __shfl(c, g * 8 + sub);
            av[g] = *(const uint4*)(A + (size_t)ri * HID + l8 * 8);
            bv[g] = *(const uint4*)(B + (size_t)ci * HID + l8 * 8);
        }

#pragma unroll
        for (int g = 0; g < 8; ++g) {
            const unsigned int* au = (const unsigned int*)&av[g];
            const unsigned int* bu = (const unsigned int*)&bv[g];
            float acc = 0.f;
#pragma unroll
            for (int i = 0; i < 4; ++i) {
                float alo = __uint_as_float(au[i] << 16);
                float ahi = __uint_as_float(au[i] & 0xffff0000u);
                float blo = __uint_as_float(bu[i] << 16);
                float bhi = __uint_as_float(bu[i] & 0xffff0000u);
                acc = fmaf(fmaxf(alo + blo, 0.f), w2r[2 * i + 0], acc);
                acc = fmaf(fmaxf(ahi + bhi, 0.f), w2r[2 * i + 1], acc);
            }
            acc += __shfl_xor(acc, 4);
            acc += __shfl_xor(acc, 2);
            acc += __shfl_xor(acc, 1);
            if (l8 == 0) out[ebase + g * 8 + sub] = acc + b2v;
        }
    }
}

extern "C" void kernel_launch(void* const* d_in, const int* in_sizes, int n_in,
                              void* d_out, int out_size, void* d_ws, size_t ws_size,
                              hipStream_t stream) {
    const float* z  = (const float*)d_in[0];
    const int*   ei = (const int*)d_in[1];
    const float* W1 = (const float*)d_in[2];
    const float* b1 = (const float*)d_in[3];
    const float* W2 = (const float*)d_in[4];
    const float* b2 = (const float*)d_in[5];
    float* out = (float*)d_out;

    const int n_nodes = in_sizes[0] / HID;     // 100000
    const int E       = in_sizes[1] / 2;       // 3200000
    const int* row = ei;
    const int* col = ei + E;

    unsigned short* A = (unsigned short*)d_ws;         // [n_nodes][64] bf16 (128B rows)
    unsigned short* B = A + (size_t)n_nodes * HID;     // [n_nodes][64] bf16

    const int nblocks = (n_nodes + 63) / 64;           // 1563, one shot
    node_proj_mfma<<<nblocks, 256, 0, stream>>>(z, W1, b1, A, B, n_nodes);
    edge_kernel<<<2048, 256, 0, stream>>>(row, col, A, B, W2, b2, out, E);
}